// Round 12
// baseline (2841.841 us; speedup 1.0000x reference)
//
#include <hip/hip_runtime.h>

typedef short short8 __attribute__((ext_vector_type(8)));
typedef float f32x4 __attribute__((ext_vector_type(4)));

#define AS1 __attribute__((address_space(1)))
#define AS3 __attribute__((address_space(3)))

// ---- workspace layout (bytes) ----
static constexpr size_t XP_OFF = 0;            // xp bf16 [T=512][G=16][B=64][Q=128] 134217728
static constexpr size_t HS_OFF = 134217728;    // hs bf16 [B*T=32768][H=512]          33554432
static constexpr size_t U_OFF  = 167772160;    // U  bf16 [P=2048][K=512]              2097152
static constexpr size_t WX_OFF = 169869312;    // WxT bf16 [P=2048][K=256]             1048576
static constexpr size_t WY_OFF = 170917888;    // WyT bf16 [N=256][K=512]               262144
static constexpr size_t BI_OFF = 171180032;    // bias fp32 [2048] (permuted)             8192
static constexpr size_t HB_OFF = 171188224;    // h ping-pong bf16 2 x [64][512]         131072
static constexpr size_t FL_OFF = 171319296;    // flags [4 rings][16 wg][4 waves] x 64B  16384
static constexpr size_t TB_OFF = 171335680;    // xcc table [256] u32                     1024
static constexpr size_t PR_OFF = 171336704;    // probe [64] x 64B                        4096
static constexpr size_t RS_OFF = 171340800;    // probe results [64] x 64B                4096

static __device__ __forceinline__ unsigned short f2bf(float f) {
  unsigned u = __float_as_uint(f);
  unsigned r = (u + 0x7fffu + ((u >> 16) & 1u)) >> 16;
  return (unsigned short)r;
}
static __device__ __forceinline__ float bf2f(unsigned short s) {
  return __uint_as_float(((unsigned)s) << 16);
}
static __device__ __forceinline__ float sigf(float x) { return 1.0f / (1.0f + __expf(-x)); }
static __device__ __forceinline__ float tanhf_(float x) { return 1.0f - 2.0f / (1.0f + __expf(2.0f * x)); }

static __device__ __forceinline__ void gld_lds16(const void* g, void* l) {
  __builtin_amdgcn_global_load_lds((const AS1 unsigned int*)g, (AS3 unsigned int*)l, 16, 0, 0);
}
// flag load embeds vmcnt(0): every poll leaves the wave's vmem counter clean.
template<int SLOW>
static __device__ __forceinline__ unsigned ldflag(const unsigned* p) {
  unsigned r;
  if constexpr (SLOW)
    asm volatile("global_load_dword %0, %1, off sc0 sc1\n\ts_waitcnt vmcnt(0)"
                 : "=v"(r) : "v"(p) : "memory");
  else
    asm volatile("global_load_dword %0, %1, off sc0\n\ts_waitcnt vmcnt(0)"
                 : "=v"(r) : "v"(p) : "memory");
  return r;
}
template<int SLOW>
static __device__ __forceinline__ void stflag(unsigned* p, unsigned v) {
  if constexpr (SLOW)
    __hip_atomic_store(p, v, __ATOMIC_RELAXED, __HIP_MEMORY_SCOPE_AGENT);
  else
    asm volatile("global_store_dword %0, %1, off sc0" :: "v"(p), "v"(v) : "memory");
}
template<int SLOW>
static __device__ __forceinline__ void sth32(void* p, unsigned v) {
  if constexpr (SLOW)
    __hip_atomic_store((unsigned*)p, v, __ATOMIC_RELAXED, __HIP_MEMORY_SCOPE_AGENT);
  else
    asm volatile("global_store_dword %0, %1, off sc0" :: "v"(p), "v"(v) : "memory");
}
// A-fragment load with immediate byte offset (no wait; caller batches + waits once)
template<int SLOW, int OFF>
static __device__ __forceinline__ short8 ldA(const char* p) {
  short8 r;
  if constexpr (SLOW)
    asm volatile("global_load_dwordx4 %0, %1, off offset:%c2 sc0 sc1"
                 : "=v"(r) : "v"(p), "i"(OFF) : "memory");
  else
    asm volatile("global_load_dwordx4 %0, %1, off offset:%c2 sc0"
                 : "=v"(r) : "v"(p), "i"(OFF) : "memory");
  return r;
}

#define DO16(M) M(0) M(1) M(2) M(3) M(4) M(5) M(6) M(7) M(8) M(9) M(10) M(11) \
  M(12) M(13) M(14) M(15)

// permuted gate column: packed p = g*128 + q, q = gate*32 + jl ; j = 32g + jl
static __device__ __forceinline__ unsigned orig_col(unsigned p) {
  return ((p & 127u) >> 5) * 512u + (p >> 7) * 32u + (p & 31u);
}

// ---------------- prep: pack weights to bf16 (permuted), biases, h0, control ----------------
__global__ void prep_kernel(const float* __restrict__ Wx, const float* __restrict__ Uh,
                            const float* __restrict__ bih, const float* __restrict__ bhh,
                            const float* __restrict__ Wy, const float* __restrict__ h0,
                            char* __restrict__ ws) {
  unsigned idx0 = blockIdx.x * blockDim.x + threadIdx.x;
  unsigned stride = gridDim.x * blockDim.x;
  unsigned short* Up = (unsigned short*)(ws + U_OFF);     // [p][k]
  for (unsigned i = idx0; i < 1048576u; i += stride) {
    unsigned k = i & 511u, p = i >> 9;
    Up[i] = f2bf(Uh[k * 2048u + orig_col(p)]);
  }
  unsigned short* Wxp = (unsigned short*)(ws + WX_OFF);   // [p][k]
  for (unsigned i = idx0; i < 524288u; i += stride) {
    unsigned k = i & 255u, p = i >> 8;
    Wxp[i] = f2bf(Wx[k * 2048u + orig_col(p)]);
  }
  unsigned short* Wyp = (unsigned short*)(ws + WY_OFF);   // [n][k]
  for (unsigned i = idx0; i < 131072u; i += stride) {
    unsigned k = i & 511u, n = i >> 9;
    Wyp[i] = f2bf(Wy[k * 256u + n]);
  }
  float* bp = (float*)(ws + BI_OFF);
  for (unsigned p = idx0; p < 2048u; p += stride) {
    unsigned c = orig_col(p);
    bp[p] = bih[c] + bhh[c];
  }
  unsigned short* hb = (unsigned short*)(ws + HB_OFF);
  for (unsigned i = idx0; i < 32768u; i += stride) hb[i] = f2bf(h0[i]);
  // zero flags + tbl + probe + res (25600 B = 6400 u32)
  for (unsigned i = idx0; i < 6400u; i += stride)
    ((unsigned*)(ws + FL_OFF))[i] = 0u;
}

// ---------------- xproj: xp[t][g=p>>7][b][q=p&127] (bf16) = x @ WxT + bias ----------------
__launch_bounds__(256, 1)
__global__ void xproj_kernel(const float* __restrict__ x, char* __restrict__ ws) {
  extern __shared__ char smem[];
  char* a_lds = smem;            // [128 r][256 k] bf16 swizzled (64KB)
  char* b_lds = smem + 65536;    // [128 p][256 k] bf16 swizzled (64KB)
  const int tid = threadIdx.x, lane = tid & 63, wid = tid >> 6;
  const int wm = wid >> 1, wn = wid & 1;
  const int r0 = blockIdx.x * 128, p0 = blockIdx.y * 128;
  const unsigned short* WxT = (const unsigned short*)(ws + WX_OFF);

#pragma unroll
  for (int i = 0; i < 16; ++i) {
    int base = i * 4096 + wid * 1024;
    int byte = base + lane * 16;
    int row = byte >> 9;
    int kb = (byte >> 4) & 31;
    gld_lds16(WxT + (size_t)(p0 + row) * 256 + (size_t)((kb ^ (row & 15)) * 8), b_lds + base);
  }
  {
    int row = tid >> 1, half = tid & 1;
    const float* xr = x + (size_t)(r0 + row) * 256 + half * 128;
    char* ar = a_lds + row * 512;
#pragma unroll
    for (int i = 0; i < 16; ++i) {
      float4 f0 = *(const float4*)(xr + i * 8);
      float4 f1 = *(const float4*)(xr + i * 8 + 4);
      short8 v;
      v[0] = (short)f2bf(f0.x); v[1] = (short)f2bf(f0.y); v[2] = (short)f2bf(f0.z); v[3] = (short)f2bf(f0.w);
      v[4] = (short)f2bf(f1.x); v[5] = (short)f2bf(f1.y); v[6] = (short)f2bf(f1.z); v[7] = (short)f2bf(f1.w);
      int kb = half * 16 + i;
      *(short8*)(ar + ((kb ^ (row & 15)) * 16)) = v;
    }
  }
  __syncthreads();

  typedef float f32x16 __attribute__((ext_vector_type(16)));
  f32x16 acc[2][2] = {};
#pragma unroll
  for (int kk = 0; kk < 16; ++kk) {
    int kbW = kk * 2 + (lane >> 5);
    short8 a[2], b[2];
#pragma unroll
    for (int mt = 0; mt < 2; ++mt) {
      int row = wm * 64 + mt * 32 + (lane & 31);
      a[mt] = *(const short8*)(a_lds + row * 512 + ((kbW ^ (row & 15)) * 16));
    }
#pragma unroll
    for (int nt = 0; nt < 2; ++nt) {
      int n = wn * 64 + nt * 32 + (lane & 31);
      b[nt] = *(const short8*)(b_lds + n * 512 + ((kbW ^ (n & 15)) * 16));
    }
#pragma unroll
    for (int mt = 0; mt < 2; ++mt)
#pragma unroll
      for (int nt = 0; nt < 2; ++nt)
        acc[mt][nt] = __builtin_amdgcn_mfma_f32_32x32x16_bf16(a[mt], b[nt], acc[mt][nt], 0, 0, 0);
  }

  const float* bias = (const float*)(ws + BI_OFF);
  unsigned short* xp = (unsigned short*)(ws + XP_OFF);
#pragma unroll
  for (int nt = 0; nt < 2; ++nt) {
    int p = p0 + wn * 64 + nt * 32 + (lane & 31);
    float bv = bias[p];
    int g = p >> 7, q = p & 127;
#pragma unroll
    for (int mt = 0; mt < 2; ++mt) {
#pragma unroll
      for (int rg = 0; rg < 16; ++rg) {
        int r = r0 + wm * 64 + mt * 32 + (rg & 3) + 8 * (rg >> 2) + 4 * (lane >> 5);
        int b = r >> 9, t = r & 511;
        xp[((size_t)(t * 16 + g) * 64 + b) * 128 + q] = f2bf(acc[mt][nt][rg] + bv);
      }
    }
  }
}

// ---------------- recurrence main loop: bulk-synchronous, direct A->VGPR ----------------
// wg (ring, g): batch rows [16*ring,+16), packed gate cols [128g,+128).
// vs R10: LDS h-staging (+its barrier, +16 ds_read) replaced by 16 direct A-frag
// loads issued in one volley (full MLP, one vmcnt(0)). vs R11: NO per-ks
// serialization — bulk poll, bulk load. Per-wave flags + per-wave publish
// (R11-validated, no end barrier). One barrier/step (gates LDS WAR).
// Gates WAR safe: wave writes gates(t+1) only after all 64 wave-flags >= t+1,
// which requires every wave's EW-read of gates(t) to have completed.
template<int SLOW>
static __device__ __forceinline__ void run_loop(char* smem, const float* c0, char* ws,
                                                float* out, int tid, int ring, int g) {
  float* gates = (float*)smem;               // [16][132] fp32 (8448B)
  const int lane = tid & 63, wid = tid >> 6;
  const int bq16 = ring * 16;
  char* hbuf = ws + HB_OFF;
  const unsigned short* xp = (const unsigned short*)(ws + XP_OFF);
  unsigned short* hs = (unsigned short*)(ws + HS_OFF);
  unsigned* flags = (unsigned*)(ws + FL_OFF);
  unsigned* myflag = flags + ((size_t)(ring * 16 + g) * 4 + wid) * 16;
  const unsigned* pollw = flags + ((size_t)(ring * 16 + (lane >> 2)) * 4 + (lane & 3)) * 16;

  // B panels: wave wid owns packed cols [g*128 + wid*32, +32); pinned in 128 VGPRs.
  short8 bU[32];   // fi = nt*16 + ks
  {
    const unsigned short* Up = (const unsigned short*)(ws + U_OFF);
    const unsigned short* pu0 = Up + (size_t)(g * 128 + wid * 32 + (lane & 15)) * 512 + (lane >> 4) * 8;
    const unsigned short* pu1 = pu0 + 16 * 512;
#define LDU0(k) asm volatile("global_load_dwordx4 %0, %1, off offset:%c2" \
                             : "=v"(bU[k]) : "v"(pu0), "i"((k) * 64) : "memory");
#define LDU1(k) asm volatile("global_load_dwordx4 %0, %1, off offset:%c2" \
                             : "=v"(bU[16 + (k)]) : "v"(pu1), "i"((k) * 64) : "memory");
    DO16(LDU0)
    DO16(LDU1)
#undef LDU0
#undef LDU1
    asm volatile("s_waitcnt vmcnt(0)" ::: "memory");
    __builtin_amdgcn_sched_barrier(0);
  }
  // elementwise ownership: thread -> (b = bq16 + bl, j = 32g + jlp, jlp+1); c in regs
  const int bl = tid >> 4, jlp = (tid & 15) * 2;
  float2 cp = *(const float2*)(c0 + (size_t)(bq16 + bl) * 512 + g * 32 + jlp);
  float cc0 = cp.x, cc1 = cp.y;
  // A-frag lane base: row = lane&15, k-offset (lane>>4)*8 elems; frag ks at +ks*64 bytes
  const char* paB = hbuf + (size_t)(bq16 + (lane & 15)) * 1024 + (lane >> 4) * 16;

  for (int t = 0; t < 512; ++t) {
    // xp loads issued first; the poll's embedded vmcnt(0) drains them (and any
    // lingering hs/out stores) before the A volley begins.
    const unsigned short* xpt = xp + ((size_t)(t * 16 + g) * 64 + (bq16 + bl)) * 128;
    ushort2 xi2 = *(const ushort2*)(xpt + jlp);
    ushort2 xf2 = *(const ushort2*)(xpt + 32 + jlp);
    ushort2 xj2 = *(const ushort2*)(xpt + 64 + jlp);
    ushort2 xo2 = *(const ushort2*)(xpt + 96 + jlp);

    // bulk poll: all 64 (wg,wave) flags >= t (one flag per lane)
    {
      unsigned tgt = (unsigned)t;
      unsigned v = ldflag<SLOW>(pollw);
      while (!__all(v >= tgt)) v = ldflag<SLOW>(pollw);
    }

    // A volley: 16 fragment loads issued back-to-back, one wait, 32 MFMAs
    const char* pa = paB + (t & 1) * 65536;
    short8 F[16];
#define LOADF(k) F[k] = ldA<SLOW, (k) * 64>(pa);
    DO16(LOADF)
#undef LOADF
    asm volatile("s_waitcnt vmcnt(0)" ::: "memory");
    __builtin_amdgcn_sched_barrier(0);
    f32x4 ac[2][2] = {};
#define MM2(k)                                                                               \
    ac[0][(k) & 1] = __builtin_amdgcn_mfma_f32_16x16x32_bf16(F[k], bU[k], ac[0][(k) & 1], 0, 0, 0); \
    ac[1][(k) & 1] = __builtin_amdgcn_mfma_f32_16x16x32_bf16(F[k], bU[16 + (k)], ac[1][(k) & 1], 0, 0, 0);
    DO16(MM2)
#undef MM2

    // gates -> LDS (wave wid owns p-cols [32wid,+32))
#pragma unroll
    for (int nt = 0; nt < 2; ++nt) {
      f32x4 facc = ac[nt][0] + ac[nt][1];
      int pl = wid * 32 + nt * 16 + (lane & 15);
      int rb = (lane >> 4) * 4;
#pragma unroll
      for (int rg = 0; rg < 4; ++rg)
        gates[(rb + rg) * 132 + pl] = facc[rg];
    }
    __syncthreads();   // the ONE barrier per step

    // elementwise LSTM cell: 2 cells/thread
    const float* gr = gates + bl * 132;
    float2 gi2 = *(const float2*)(gr + jlp);
    float2 gf2 = *(const float2*)(gr + 32 + jlp);
    float2 gj2 = *(const float2*)(gr + 64 + jlp);
    float2 go2 = *(const float2*)(gr + 96 + jlp);
    float i0 = sigf(gi2.x + bf2f(xi2.x)), i1 = sigf(gi2.y + bf2f(xi2.y));
    float f0 = sigf(gf2.x + bf2f(xf2.x)), f1 = sigf(gf2.y + bf2f(xf2.y));
    float j0v = tanhf_(gj2.x + bf2f(xj2.x)), j1v = tanhf_(gj2.y + bf2f(xj2.y));
    float o0 = sigf(go2.x + bf2f(xo2.x)), o1 = sigf(go2.y + bf2f(xo2.y));
    cc0 = f0 * cc0 + i0 * j0v;
    cc1 = f1 * cc1 + i1 * j1v;
    float h0v = o0 * tanhf_(cc0);
    float h1v = o1 * tanhf_(cc1);
    unsigned hv = (unsigned)f2bf(h0v) | ((unsigned)f2bf(h1v) << 16);

    // h -> ping-pong slot (t+1)&1; per-wave drain; per-wave flag publish (no barrier)
    if (t < 511)
      sth32<SLOW>(hbuf + ((t + 1) & 1) * 65536 +
                  ((size_t)(bq16 + bl) * 512 + g * 32 + jlp) * 2, hv);
    asm volatile("s_waitcnt vmcnt(0)" ::: "memory");
    if ((lane & 63) == 0) stflag<SLOW>(myflag, (unsigned)(t + 1));
    // fire-and-forget records (drained by next step's poll)
    *(unsigned*)(hs + ((size_t)(bq16 + bl) * 512 + t) * 512 + g * 32 + jlp) = hv;
    if (t == 511) {
      *(float2*)(out + 8388608u + (size_t)(bq16 + bl) * 512 + g * 32 + jlp) = make_float2(h0v, h1v);
      *(float2*)(out + 8421376u + (size_t)(bq16 + bl) * 512 + g * 32 + jlp) = make_float2(cc0, cc1);
    }
  }
}

// 256 wgs register their XCD; all derive the same assignment: 4 rings x 16 members,
// each ring on one XCD (first 4 XCD values with >=16 wgs; else forced-slow on bids
// 0..63). Each ring independently probes sc0 visibility (bounded) and collectively
// picks fast (XCD-L2) or slow (device-scope). Rings never communicate. (R10-proven.)
__launch_bounds__(256, 1)
__global__ void lstm_rec_kernel(const float* __restrict__ c0, char* __restrict__ ws,
                                float* __restrict__ out) {
  extern __shared__ char smem[];   // control: ldsT 1024 | ldsF 64 (reuses gates area)
  unsigned* ldsT = (unsigned*)smem;
  unsigned* ldsF = (unsigned*)(smem + 1024);
  const int tid = threadIdx.x, lane = tid & 63, wid = tid >> 6;
  const int bid = blockIdx.x;

  // phase 0: registration
  unsigned* tbl = (unsigned*)(ws + TB_OFF);
  unsigned xcc;
  asm volatile("s_getreg_b32 %0, hwreg(HW_REG_XCC_ID)" : "=s"(xcc));
  if (tid == 0)
    __hip_atomic_store(tbl + bid, (xcc & 15u) + 1u, __ATOMIC_RELAXED, __HIP_MEMORY_SCOPE_AGENT);
  if (wid == 0) {
    for (;;) {
      unsigned v0 = __hip_atomic_load(tbl + lane, __ATOMIC_RELAXED, __HIP_MEMORY_SCOPE_AGENT);
      unsigned v1 = __hip_atomic_load(tbl + 64 + lane, __ATOMIC_RELAXED, __HIP_MEMORY_SCOPE_AGENT);
      unsigned v2 = __hip_atomic_load(tbl + 128 + lane, __ATOMIC_RELAXED, __HIP_MEMORY_SCOPE_AGENT);
      unsigned v3 = __hip_atomic_load(tbl + 192 + lane, __ATOMIC_RELAXED, __HIP_MEMORY_SCOPE_AGENT);
      ldsT[lane] = v0; ldsT[64 + lane] = v1; ldsT[128 + lane] = v2; ldsT[192 + lane] = v3;
      if (__all((v0 != 0u) && (v1 != 0u) && (v2 != 0u) && (v3 != 0u))) break;
    }
  }
  __syncthreads();

  // phase 1: deterministic assignment (identical on every thread)
  int ringXcd[4] = {0, 0, 0, 0};
  int nr = 0;
  for (int x = 1; x <= 16; ++x) {
    int cnt = 0;
    for (int b = 0; b < 256; ++b) cnt += (ldsT[b] == (unsigned)x) ? 1 : 0;
    if (cnt >= 16 && nr < 4) ringXcd[nr++] = x;
  }
  bool slowForce = (nr < 4);
  int ring = 0, g = 0;
  bool sel = false;
  if (slowForce) {
    sel = (bid < 64);
    ring = bid >> 4;
    g = bid & 15;
  } else {
    unsigned myx = ldsT[bid];
    int r = -1;
    for (int i = 0; i < 4; ++i)
      if (ringXcd[i] == (int)myx) r = i;
    if (r >= 0) {
      int rank = 0;
      for (int b = 0; b < bid; ++b) rank += (ldsT[b] == myx) ? 1 : 0;
      if (rank < 16) { sel = true; ring = r; g = rank; }
    }
  }
  if (!sel) return;

  // phase 2: per-ring bounded probe of sc0 visibility, then collective decision
  bool fast = false;
  if (!slowForce) {
    unsigned* probe = (unsigned*)(ws + PR_OFF);
    if (tid == 0) stflag<0>(probe + (size_t)(ring * 16 + g) * 16, 1u);
    asm volatile("s_waitcnt vmcnt(0)" ::: "memory");
    if (wid == 0) {
      int ok = 0;
      for (int it = 0; it < 4096; ++it) {
        unsigned v = ldflag<0>(probe + (size_t)(ring * 16 + (lane & 15)) * 16);
        if (__all(v != 0u)) { ok = 1; break; }
      }
      if (lane == 0) ldsF[0] = (unsigned)ok;
    }
    __syncthreads();
    unsigned ok = ldsF[0];
    unsigned* res = (unsigned*)(ws + RS_OFF);
    if (tid == 0) stflag<1>(res + (size_t)(ring * 16 + g) * 16, ok ? 2u : 1u);
    if (wid == 0) {
      unsigned v;
      do {
        v = __hip_atomic_load((unsigned*)(ws + RS_OFF) + (size_t)(ring * 16 + (lane & 15)) * 16,
                              __ATOMIC_RELAXED, __HIP_MEMORY_SCOPE_AGENT);
      } while (__any(v == 0u));
      if (lane == 0) ldsF[1] = __all(v == 2u) ? 1u : 0u;
    }
    __syncthreads();
    fast = (ldsF[1] != 0u);
  }
  __syncthreads();

  if (fast) run_loop<0>(smem, c0, (char*)ws, out, tid, ring, g);
  else      run_loop<1>(smem, c0, (char*)ws, out, tid, ring, g);
}

// ---------------- ygemm: out[r][o] = hs @ WyT + b_y ----------------
__launch_bounds__(256, 1)
__global__ void ygemm_kernel(const char* __restrict__ ws, const float* __restrict__ by,
                             float* __restrict__ out) {
  extern __shared__ char smem[];
  char* a_lds = smem;            // [128][128] bf16 swizzled (32KB)
  char* b_lds = smem + 32768;    // [128][128] bf16 swizzled (32KB)
  const int tid = threadIdx.x, lane = tid & 63, wid = tid >> 6;
  const int wm = wid >> 1, wn = wid & 1;
  const int r0 = blockIdx.x * 128, n0 = blockIdx.y * 128;
  const unsigned short* hs = (const unsigned short*)(ws + HS_OFF);
  const unsigned short* WyT = (const unsigned short*)(ws + WY_OFF);

  typedef float f32x16 __attribute__((ext_vector_type(16)));
  f32x16 acc[2][2] = {};
  for (int k0 = 0; k0 < 512; k0 += 128) {
#pragma unroll
    for (int i = 0; i < 8; ++i) {
      int base = i * 4096 + wid * 1024;
      int byte = base + lane * 16;
      int row = byte >> 8;
      int kb = (byte >> 4) & 15;
      gld_lds16(hs + (size_t)(r0 + row) * 512 + k0 + ((kb ^ (row & 15)) * 8), a_lds + base);
      gld_lds16(WyT + (size_t)(n0 + row) * 512 + k0 + ((kb ^ (row & 15)) * 8), b_lds + base);
    }
    __syncthreads();
#pragma unroll
    for (int kk = 0; kk < 8; ++kk) {
      int kbW = kk * 2 + (lane >> 5);
      short8 a[2], b[2];
#pragma unroll
      for (int mt = 0; mt < 2; ++mt) {
        int row = wm * 64 + mt * 32 + (lane & 31);
        a[mt] = *(const short8*)(a_lds + row * 256 + ((kbW ^ (row & 15)) * 16));
        int n = wn * 64 + mt * 32 + (lane & 31);
        b[mt] = *(const short8*)(b_lds + n * 256 + ((kbW ^ (n & 15)) * 16));
      }
#pragma unroll
      for (int mt = 0; mt < 2; ++mt)
#pragma unroll
        for (int nt = 0; nt < 2; ++nt)
          acc[mt][nt] = __builtin_amdgcn_mfma_f32_32x32x16_bf16(a[mt], b[nt], acc[mt][nt], 0, 0, 0);
    }
    __syncthreads();
  }
#pragma unroll
  for (int nt = 0; nt < 2; ++nt) {
    int o = n0 + wn * 64 + nt * 32 + (lane & 31);
    float bv = by[o];
#pragma unroll
    for (int mt = 0; mt < 2; ++mt)
#pragma unroll
      for (int rg = 0; rg < 16; ++rg) {
        int r = r0 + wm * 64 + mt * 32 + (rg & 3) + 8 * (rg >> 2) + 4 * (lane >> 5);
        out[(size_t)r * 256 + o] = acc[mt][nt][rg] + bv;
      }
  }
}

extern "C" void kernel_launch(void* const* d_in, const int* in_sizes, int n_in,
                              void* d_out, int out_size, void* d_ws, size_t ws_size,
                              hipStream_t stream) {
  (void)in_sizes; (void)n_in; (void)out_size; (void)ws_size;
  const float* x   = (const float*)d_in[0];
  const float* h0  = (const float*)d_in[1];
  const float* c0  = (const float*)d_in[2];
  const float* Wx  = (const float*)d_in[3];
  const float* Uh  = (const float*)d_in[4];
  const float* bih = (const float*)d_in[5];
  const float* bhh = (const float*)d_in[6];
  const float* Wy  = (const float*)d_in[7];
  const float* by  = (const float*)d_in[8];
  char* ws = (char*)d_ws;
  float* out = (float*)d_out;

  prep_kernel<<<1024, 256, 0, stream>>>(Wx, Uh, bih, bhh, Wy, h0, ws);
  xproj_kernel<<<dim3(256, 16), 256, 131072, stream>>>(x, ws);
  lstm_rec_kernel<<<256, 256, 8448, stream>>>(c0, ws, out);
  ygemm_kernel<<<dim3(256, 2), 256, 65536, stream>>>(ws, by, out);
}

// Round 15
// 2618.410 us; speedup vs baseline: 1.0853x; 1.0853x over previous
//
#include <hip/hip_runtime.h>

typedef short short8 __attribute__((ext_vector_type(8)));
typedef float f32x4 __attribute__((ext_vector_type(4)));

#define AS1 __attribute__((address_space(1)))
#define AS3 __attribute__((address_space(3)))

// ---- workspace layout (bytes) ----
static constexpr size_t XP_OFF = 0;            // xp bf16 [T=512][G=16][B=64][jl=32][gate=4] 134217728
static constexpr size_t HS_OFF = 134217728;    // hs bf16 [B*T=32768][H=512]          33554432
static constexpr size_t U_OFF  = 167772160;    // U  bf16 [P=2048][K=512]              2097152
static constexpr size_t WX_OFF = 169869312;    // WxT bf16 [P=2048][K=256]             1048576
static constexpr size_t WY_OFF = 170917888;    // WyT bf16 [N=256][K=512]               262144
static constexpr size_t BI_OFF = 171180032;    // bias fp32 [2048] (permuted)             8192
static constexpr size_t HB_OFF = 171188224;    // h ping-pong bf16 2 x [64][512]         131072
static constexpr size_t FL_OFF = 171319296;    // flags [64 consumer wg][64 producer wave] x 64B  262144
static constexpr size_t TB_OFF = 171581440;    // xcc table [256] u32                     1024
static constexpr size_t PR_OFF = 171582464;    // probe [64] x 64B                        4096
static constexpr size_t RS_OFF = 171586560;    // probe results [64] x 64B                4096

static __device__ __forceinline__ unsigned short f2bf(float f) {
  unsigned u = __float_as_uint(f);
  unsigned r = (u + 0x7fffu + ((u >> 16) & 1u)) >> 16;
  return (unsigned short)r;
}
static __device__ __forceinline__ float bf2f(unsigned short s) {
  return __uint_as_float(((unsigned)s) << 16);
}
static __device__ __forceinline__ float sigf(float x) { return 1.0f / (1.0f + __expf(-x)); }
static __device__ __forceinline__ float tanhf_(float x) { return 1.0f - 2.0f / (1.0f + __expf(2.0f * x)); }

static __device__ __forceinline__ void gld_lds16(const void* g, void* l) {
  __builtin_amdgcn_global_load_lds((const AS1 unsigned int*)g, (AS3 unsigned int*)l, 16, 0, 0);
}
template<int SLOW>
static __device__ __forceinline__ void gld_lds16_c(const void* g, void* l) {
  if constexpr (SLOW)
    __builtin_amdgcn_global_load_lds((const AS1 unsigned int*)g, (AS3 unsigned int*)l, 16, 0, 17);
  else
    __builtin_amdgcn_global_load_lds((const AS1 unsigned int*)g, (AS3 unsigned int*)l, 16, 0, 1);
}
template<int SLOW>
static __device__ __forceinline__ unsigned ldflag(const unsigned* p) {
  unsigned r;
  if constexpr (SLOW)
    asm volatile("global_load_dword %0, %1, off sc0 sc1\n\ts_waitcnt vmcnt(0)"
                 : "=v"(r) : "v"(p) : "memory");
  else
    asm volatile("global_load_dword %0, %1, off sc0\n\ts_waitcnt vmcnt(0)"
                 : "=v"(r) : "v"(p) : "memory");
  return r;
}
template<int SLOW>
static __device__ __forceinline__ void stflag(unsigned* p, unsigned v) {
  if constexpr (SLOW)
    __hip_atomic_store(p, v, __ATOMIC_RELAXED, __HIP_MEMORY_SCOPE_AGENT);
  else
    asm volatile("global_store_dword %0, %1, off sc0" :: "v"(p), "v"(v) : "memory");
}
template<int SLOW>
static __device__ __forceinline__ void sth64(void* p, unsigned long long v) {
  if constexpr (SLOW)
    __hip_atomic_store((unsigned long long*)p, v, __ATOMIC_RELAXED, __HIP_MEMORY_SCOPE_AGENT);
  else
    asm volatile("global_store_dwordx2 %0, %1, off sc0" :: "v"(p), "v"(v) : "memory");
}

#define DO16(M) M(0) M(1) M(2) M(3) M(4) M(5) M(6) M(7) M(8) M(9) M(10) M(11) \
  M(12) M(13) M(14) M(15)

// gate-interleaved packed order: P = g*128 + wid*32 + n*16 + c;
// gate = n*2 + (c>>3); jl = wid*8 + (c&7); orig col = gate*512 + g*32 + jl.
// (Each wave's two 16-col tiles carry all 4 gates of its own 8 hidden cols.)
static __device__ __forceinline__ unsigned orig_col(unsigned p) {
  unsigned pw = p & 127u, g = p >> 7;
  unsigned wid = pw >> 5, n = (pw >> 4) & 1u, c = pw & 15u;
  unsigned gate = n * 2u + (c >> 3);
  unsigned jl = wid * 8u + (c & 7u);
  return gate * 512u + g * 32u + jl;
}

// ---------------- prep ----------------
__global__ void prep_kernel(const float* __restrict__ Wx, const float* __restrict__ Uh,
                            const float* __restrict__ bih, const float* __restrict__ bhh,
                            const float* __restrict__ Wy, const float* __restrict__ h0,
                            char* __restrict__ ws) {
  unsigned idx0 = blockIdx.x * blockDim.x + threadIdx.x;
  unsigned stride = gridDim.x * blockDim.x;
  unsigned short* Up = (unsigned short*)(ws + U_OFF);     // [p][k]
  for (unsigned i = idx0; i < 1048576u; i += stride) {
    unsigned k = i & 511u, p = i >> 9;
    Up[i] = f2bf(Uh[k * 2048u + orig_col(p)]);
  }
  unsigned short* Wxp = (unsigned short*)(ws + WX_OFF);   // [p][k]
  for (unsigned i = idx0; i < 524288u; i += stride) {
    unsigned k = i & 255u, p = i >> 8;
    Wxp[i] = f2bf(Wx[k * 2048u + orig_col(p)]);
  }
  unsigned short* Wyp = (unsigned short*)(ws + WY_OFF);   // [n][k]
  for (unsigned i = idx0; i < 131072u; i += stride) {
    unsigned k = i & 511u, n = i >> 9;
    Wyp[i] = f2bf(Wy[k * 256u + n]);
  }
  float* bp = (float*)(ws + BI_OFF);
  for (unsigned p = idx0; p < 2048u; p += stride) {
    unsigned c = orig_col(p);
    bp[p] = bih[c] + bhh[c];
  }
  unsigned short* hb = (unsigned short*)(ws + HB_OFF);
  for (unsigned i = idx0; i < 32768u; i += stride) hb[i] = f2bf(h0[i]);
  // zero flags + tbl + probe + res ((262144+1024+4096+4096)/4 = 67840 u32)
  for (unsigned i = idx0; i < 67840u; i += stride)
    ((unsigned*)(ws + FL_OFF))[i] = 0u;
}

// ---------------- xproj: xp[t][g][b][jl][gate] (bf16) = x @ WxT + bias ----------------
__launch_bounds__(256, 1)
__global__ void xproj_kernel(const float* __restrict__ x, char* __restrict__ ws) {
  extern __shared__ char smem[];
  char* a_lds = smem;            // [128 r][256 k] bf16 swizzled (64KB)
  char* b_lds = smem + 65536;    // [128 p][256 k] bf16 swizzled (64KB)
  const int tid = threadIdx.x, lane = tid & 63, wid = tid >> 6;
  const int wm = wid >> 1, wn = wid & 1;
  const int r0 = blockIdx.x * 128, p0 = blockIdx.y * 128;
  const unsigned short* WxT = (const unsigned short*)(ws + WX_OFF);

#pragma unroll
  for (int i = 0; i < 16; ++i) {
    int base = i * 4096 + wid * 1024;
    int byte = base + lane * 16;
    int row = byte >> 9;
    int kb = (byte >> 4) & 31;
    gld_lds16(WxT + (size_t)(p0 + row) * 256 + (size_t)((kb ^ (row & 15)) * 8), b_lds + base);
  }
  {
    int row = tid >> 1, half = tid & 1;
    const float* xr = x + (size_t)(r0 + row) * 256 + half * 128;
    char* ar = a_lds + row * 512;
#pragma unroll
    for (int i = 0; i < 16; ++i) {
      float4 f0 = *(const float4*)(xr + i * 8);
      float4 f1 = *(const float4*)(xr + i * 8 + 4);
      short8 v;
      v[0] = (short)f2bf(f0.x); v[1] = (short)f2bf(f0.y); v[2] = (short)f2bf(f0.z); v[3] = (short)f2bf(f0.w);
      v[4] = (short)f2bf(f1.x); v[5] = (short)f2bf(f1.y); v[6] = (short)f2bf(f1.z); v[7] = (short)f2bf(f1.w);
      int kb = half * 16 + i;
      *(short8*)(ar + ((kb ^ (row & 15)) * 16)) = v;
    }
  }
  __syncthreads();

  typedef float f32x16 __attribute__((ext_vector_type(16)));
  f32x16 acc[2][2] = {};
#pragma unroll
  for (int kk = 0; kk < 16; ++kk) {
    int kbW = kk * 2 + (lane >> 5);
    short8 a[2], b[2];
#pragma unroll
    for (int mt = 0; mt < 2; ++mt) {
      int row = wm * 64 + mt * 32 + (lane & 31);
      a[mt] = *(const short8*)(a_lds + row * 512 + ((kbW ^ (row & 15)) * 16));
    }
#pragma unroll
    for (int nt = 0; nt < 2; ++nt) {
      int n = wn * 64 + nt * 32 + (lane & 31);
      b[nt] = *(const short8*)(b_lds + n * 512 + ((kbW ^ (n & 15)) * 16));
    }
#pragma unroll
    for (int mt = 0; mt < 2; ++mt)
#pragma unroll
      for (int nt = 0; nt < 2; ++nt)
        acc[mt][nt] = __builtin_amdgcn_mfma_f32_32x32x16_bf16(a[mt], b[nt], acc[mt][nt], 0, 0, 0);
  }

  const float* bias = (const float*)(ws + BI_OFF);
  unsigned short* xp = (unsigned short*)(ws + XP_OFF);
#pragma unroll
  for (int nt = 0; nt < 2; ++nt) {
    int p = p0 + wn * 64 + nt * 32 + (lane & 31);
    float bv = bias[p];
    int g = p >> 7, pw = p & 127;
    int widp = pw >> 5, np = (pw >> 4) & 1, cq = pw & 15;
    int gate = np * 2 + (cq >> 3);
    int jl = widp * 8 + (cq & 7);
    int qx = jl * 4 + gate;
#pragma unroll
    for (int mt = 0; mt < 2; ++mt) {
#pragma unroll
      for (int rg = 0; rg < 16; ++rg) {
        int r = r0 + wm * 64 + mt * 32 + (rg & 3) + 8 * (rg >> 2) + 4 * (lane >> 5);
        int b = r >> 9, t = r & 511;
        xp[((size_t)(t * 16 + g) * 64 + b) * 128 + qx] = f2bf(acc[mt][nt][rg] + bv);
      }
    }
  }
}

// ---------------- recurrence: R10 staging skeleton + in-wave EW, 1 barrier/step ----------------
// wg (ring, g): batch rows [16*ring,+16), hidden cols [32g,+32). Wave wid owns
// jl in [8wid,+8): tile0 = {i|f}, tile1 = {j|o} gates (prep permutation). After
// MFMA, shfl_xor(8) gives each lane all 4 gates -> EW in-register (no gates LDS,
// no barrier). Butterfly 4x4 transpose -> one 8B h store per active lane.
// Per-wave flags published after per-wave drain to 16 per-consumer replicas
// (private poll lines, no shared-line contention). Parity-double-buffered LDS;
// t/t-2 overwrite safety by the flag induction (flag>=t implies stage(t-1) done).
template<int SLOW>
static __device__ __forceinline__ void run_loop(char* smem, const float* c0, char* ws,
                                                float* out, int tid, int ring, int g) {
  char* h_lds2 = smem;                       // [2][16][1024] (32KB)
  const int lane = tid & 63, wid = tid >> 6;
  const int bq16 = ring * 16;
  char* hbuf = ws + HB_OFF;
  const unsigned short* xp = (const unsigned short*)(ws + XP_OFF);
  unsigned short* hs = (unsigned short*)(ws + HS_OFF);
  unsigned* flags = (unsigned*)(ws + FL_OFF);
  // publish: lane<16 stores this wave's flag into consumer lane's private copy
  unsigned* pubp = flags + ((size_t)(ring * 16 + (lane & 15)) * 64 + (g * 4 + wid)) * 16;
  // poll: lane reads producer wave `lane` from own wg's private copies
  const unsigned* pollp = flags + ((size_t)(ring * 16 + g) * 64 + lane) * 16;

  // B panels: wave wid owns packed cols [g*128+wid*32, +32) (2 tiles); 128 VGPRs.
  short8 bU[32];   // [n*16 + ks]
  {
    const unsigned short* Up = (const unsigned short*)(ws + U_OFF);
    const unsigned short* pu0 = Up + (size_t)(g * 128 + wid * 32 + (lane & 15)) * 512 + (lane >> 4) * 8;
    const unsigned short* pu1 = pu0 + 16 * 512;
#define LDU0(k) asm volatile("global_load_dwordx4 %0, %1, off offset:%c2" \
                             : "=v"(bU[k]) : "v"(pu0), "i"((k) * 64) : "memory");
#define LDU1(k) asm volatile("global_load_dwordx4 %0, %1, off offset:%c2" \
                             : "=v"(bU[16 + (k)]) : "v"(pu1), "i"((k) * 64) : "memory");
    DO16(LDU0)
    DO16(LDU1)
#undef LDU0
#undef LDU1
    asm volatile("s_waitcnt vmcnt(0)" ::: "memory");
    __builtin_amdgcn_sched_barrier(0);
  }

  const int c = lane & 15, rg = lane >> 4;
  const bool active = (c < 8);
  const int jl = wid * 8 + (c & 7);          // this lane's hidden col (pre-transpose)
  const int q = (c >> 2) & 1;                // 4-col block within the wave's 8
  const bool odd = (c & 1), hi = ((c >> 1) & 1);
  // c-state: 4 batch rows (4rg..4rg+3) x 1 col jl (valid on active lanes)
  float cc[4];
#pragma unroll
  for (int r = 0; r < 4; ++r)
    cc[r] = c0[(size_t)(bq16 + 4 * rg + r) * 512 + g * 32 + jl];

  for (int t = 0; t < 512; ++t) {
    // xp: 4 gates x 4 batch rows for col jl (bias already folded in)
    const unsigned short* xpt = xp + ((size_t)(t * 16 + g) * 64 + (bq16 + 4 * rg)) * 128 + jl * 4;
    ushort4 xg0 = *(const ushort4*)(xpt);
    ushort4 xg1 = *(const ushort4*)(xpt + 128);
    ushort4 xg2 = *(const ushort4*)(xpt + 256);
    ushort4 xg3 = *(const ushort4*)(xpt + 384);

    // poll: all 64 producer-wave flags >= t (private replicas; embeds vmcnt(0))
    {
      unsigned tgt = (unsigned)t;
      unsigned v = ldflag<SLOW>(pollp);
      while (!__all(v >= tgt)) v = ldflag<SLOW>(pollp);
    }
    // stage 16 rows of slot t&1 into LDS half t&1 (wave wid rows [4wid,+4))
    char* hl = h_lds2 + (t & 1) * 16384;
    const char* hb = hbuf + (t & 1) * 65536;
#pragma unroll
    for (int i = 0; i < 4; ++i) {
      int r = wid * 4 + i;
      gld_lds16_c<SLOW>(hb + (size_t)(bq16 + r) * 1024 + ((lane ^ r) * 16), hl + r * 1024);
    }
    __syncthreads();   // the ONE barrier per step (drains staging)

    // GEMM [16 x 512] x [512 x 32]: 16 k-steps, 2 tiles
    f32x4 ac[2][2] = {};
#pragma unroll
    for (int ks = 0; ks < 16; ++ks) {
      int row = lane & 15;
      int gi = (ks * 4 + rg) ^ row;
      short8 a = *(const short8*)(hl + row * 1024 + gi * 16);
      ac[0][ks & 1] = __builtin_amdgcn_mfma_f32_16x16x32_bf16(a, bU[ks], ac[0][ks & 1], 0, 0, 0);
      ac[1][ks & 1] = __builtin_amdgcn_mfma_f32_16x16x32_bf16(a, bU[16 + ks], ac[1][ks & 1], 0, 0, 0);
    }
    f32x4 f0v = ac[0][0] + ac[0][1];   // c<8: gate i   | c>=8: gate f
    f32x4 f1v = ac[1][0] + ac[1][1];   // c<8: gate j   | c>=8: gate o
    // gate swap within wave: each active lane gets its f and o halves
    f32x4 o0v, o1v;
#pragma unroll
    for (int r = 0; r < 4; ++r) {
      o0v[r] = __shfl_xor(f0v[r], 8);
      o1v[r] = __shfl_xor(f1v[r], 8);
    }
    // EW (valid on active lanes; inactive compute garbage, never stored)
    float v0, v1, v2, v3;
    {
      float iv, fv, jv, ov, cn;
      iv = sigf(f0v[0] + bf2f(xg0.x)); fv = sigf(o0v[0] + bf2f(xg0.y));
      jv = tanhf_(f1v[0] + bf2f(xg0.z)); ov = sigf(o1v[0] + bf2f(xg0.w));
      cn = fv * cc[0] + iv * jv; cc[0] = cn; v0 = ov * tanhf_(cn);
      iv = sigf(f0v[1] + bf2f(xg1.x)); fv = sigf(o0v[1] + bf2f(xg1.y));
      jv = tanhf_(f1v[1] + bf2f(xg1.z)); ov = sigf(o1v[1] + bf2f(xg1.w));
      cn = fv * cc[1] + iv * jv; cc[1] = cn; v1 = ov * tanhf_(cn);
      iv = sigf(f0v[2] + bf2f(xg2.x)); fv = sigf(o0v[2] + bf2f(xg2.y));
      jv = tanhf_(f1v[2] + bf2f(xg2.z)); ov = sigf(o1v[2] + bf2f(xg2.w));
      cn = fv * cc[2] + iv * jv; cc[2] = cn; v2 = ov * tanhf_(cn);
      iv = sigf(f0v[3] + bf2f(xg3.x)); fv = sigf(o0v[3] + bf2f(xg3.y));
      jv = tanhf_(f1v[3] + bf2f(xg3.z)); ov = sigf(o1v[3] + bf2f(xg3.w));
      cn = fv * cc[3] + iv * jv; cc[3] = cn; v3 = ov * tanhf_(cn);
    }
    // 4x4 butterfly transpose among lanes u=c&3 (stage A xor1, stage B xor2):
    // after: lane u holds h[b=4rg+u][jlbase + 0..3], jlbase = 8wid + 4q
    {
      float sA0 = odd ? v0 : v1, sA1 = odd ? v2 : v3;
      float rA0 = __shfl_xor(sA0, 1), rA1 = __shfl_xor(sA1, 1);
      v0 = odd ? rA0 : v0;  v1 = odd ? v1 : rA0;
      v2 = odd ? rA1 : v2;  v3 = odd ? v3 : rA1;
      float sB0 = hi ? v0 : v2, sB1 = hi ? v1 : v3;
      float rB0 = __shfl_xor(sB0, 2), rB1 = __shfl_xor(sB1, 2);
      v0 = hi ? rB0 : v0;  v1 = hi ? rB1 : v1;
      v2 = hi ? v2 : rB0;  v3 = hi ? v3 : rB1;
    }
    const int bT = bq16 + 4 * rg + (c & 3);          // transposed row (batch)
    const int jT = g * 32 + wid * 8 + 4 * q;         // transposed col base
    unsigned long long hpk;
    {
      union { unsigned short u[4]; unsigned long long ll; } pk;
      pk.u[0] = f2bf(v0); pk.u[1] = f2bf(v1); pk.u[2] = f2bf(v2); pk.u[3] = f2bf(v3);
      hpk = pk.ll;
    }
    if (active) {
      sth64<SLOW>(hbuf + ((t + 1) & 1) * 65536 + (size_t)bT * 1024 + (size_t)jT * 2, hpk);
      if (t == 511) {
        *(float4*)(out + 8388608u + (size_t)bT * 512 + jT) = make_float4(v0, v1, v2, v3);
#pragma unroll
        for (int r = 0; r < 4; ++r)
          out[8421376u + (size_t)(bq16 + 4 * rg + r) * 512 + g * 32 + jl] = cc[r];
      }
    }
    // per-wave drain, then publish to the 16 consumer replicas (1 instr)
    asm volatile("s_waitcnt vmcnt(0)" ::: "memory");
    if ((lane & 63) < 16) stflag<SLOW>(pubp, (unsigned)(t + 1));
    // hs record: fire-and-forget (drained by next poll's vmcnt0)
    if (active)
      *(unsigned long long*)(hs + ((size_t)bT * 512 + t) * 512 + jT) = hpk;
  }
}

// 256 wgs register their XCD; 4 rings x 16 members, each ring on one XCD (else
// forced-slow on bids 0..63). Per-ring bounded probe of sc0 visibility, then
// collective fast/slow decision via device scope. (R10-proven verbatim.)
__launch_bounds__(256, 1)
__global__ void lstm_rec_kernel(const float* __restrict__ c0, char* __restrict__ ws,
                                float* __restrict__ out) {
  extern __shared__ char smem[];   // control (ldsT 1024 | ldsF 64) overlaps h_lds
  unsigned* ldsT = (unsigned*)smem;
  unsigned* ldsF = (unsigned*)(smem + 1024);
  const int tid = threadIdx.x, lane = tid & 63, wid = tid >> 6;
  const int bid = blockIdx.x;

  unsigned* tbl = (unsigned*)(ws + TB_OFF);
  unsigned xcc;
  asm volatile("s_getreg_b32 %0, hwreg(HW_REG_XCC_ID)" : "=s"(xcc));
  if (tid == 0)
    __hip_atomic_store(tbl + bid, (xcc & 15u) + 1u, __ATOMIC_RELAXED, __HIP_MEMORY_SCOPE_AGENT);
  if (wid == 0) {
    for (;;) {
      unsigned v0 = __hip_atomic_load(tbl + lane, __ATOMIC_RELAXED, __HIP_MEMORY_SCOPE_AGENT);
      unsigned v1 = __hip_atomic_load(tbl + 64 + lane, __ATOMIC_RELAXED, __HIP_MEMORY_SCOPE_AGENT);
      unsigned v2 = __hip_atomic_load(tbl + 128 + lane, __ATOMIC_RELAXED, __HIP_MEMORY_SCOPE_AGENT);
      unsigned v3 = __hip_atomic_load(tbl + 192 + lane, __ATOMIC_RELAXED, __HIP_MEMORY_SCOPE_AGENT);
      ldsT[lane] = v0; ldsT[64 + lane] = v1; ldsT[128 + lane] = v2; ldsT[192 + lane] = v3;
      if (__all((v0 != 0u) && (v1 != 0u) && (v2 != 0u) && (v3 != 0u))) break;
    }
  }
  __syncthreads();

  int ringXcd[4] = {0, 0, 0, 0};
  int nr = 0;
  for (int x = 1; x <= 16; ++x) {
    int cnt = 0;
    for (int b = 0; b < 256; ++b) cnt += (ldsT[b] == (unsigned)x) ? 1 : 0;
    if (cnt >= 16 && nr < 4) ringXcd[nr++] = x;
  }
  bool slowForce = (nr < 4);
  int ring = 0, g = 0;
  bool sel = false;
  if (slowForce) {
    sel = (bid < 64);
    ring = bid >> 4;
    g = bid & 15;
  } else {
    unsigned myx = ldsT[bid];
    int r = -1;
    for (int i = 0; i < 4; ++i)
      if (ringXcd[i] == (int)myx) r = i;
    if (r >= 0) {
      int rank = 0;
      for (int b = 0; b < bid; ++b) rank += (ldsT[b] == myx) ? 1 : 0;
      if (rank < 16) { sel = true; ring = r; g = rank; }
    }
  }
  if (!sel) return;

  bool fast = false;
  if (!slowForce) {
    unsigned* probe = (unsigned*)(ws + PR_OFF);
    if (tid == 0) stflag<0>(probe + (size_t)(ring * 16 + g) * 16, 1u);
    asm volatile("s_waitcnt vmcnt(0)" ::: "memory");
    if (wid == 0) {
      int ok = 0;
      for (int it = 0; it < 4096; ++it) {
        unsigned v = ldflag<0>(probe + (size_t)(ring * 16 + (lane & 15)) * 16);
        if (__all(v != 0u)) { ok = 1; break; }
      }
      if (lane == 0) ldsF[0] = (unsigned)ok;
    }
    __syncthreads();
    unsigned ok = ldsF[0];
    unsigned* res = (unsigned*)(ws + RS_OFF);
    if (tid == 0) stflag<1>(res + (size_t)(ring * 16 + g) * 16, ok ? 2u : 1u);
    if (wid == 0) {
      unsigned v;
      do {
        v = __hip_atomic_load((unsigned*)(ws + RS_OFF) + (size_t)(ring * 16 + (lane & 15)) * 16,
                              __ATOMIC_RELAXED, __HIP_MEMORY_SCOPE_AGENT);
      } while (__any(v == 0u));
      if (lane == 0) ldsF[1] = __all(v == 2u) ? 1u : 0u;
    }
    __syncthreads();
    fast = (ldsF[1] != 0u);
  }
  __syncthreads();

  if (fast) run_loop<0>(smem, c0, (char*)ws, out, tid, ring, g);
  else      run_loop<1>(smem, c0, (char*)ws, out, tid, ring, g);
}

// ---------------- ygemm: out[r][o] = hs @ WyT + b_y ----------------
__launch_bounds__(256, 1)
__global__ void ygemm_kernel(const char* __restrict__ ws, const float* __restrict__ by,
                             float* __restrict__ out) {
  extern __shared__ char smem[];
  char* a_lds = smem;            // [128][128] bf16 swizzled (32KB)
  char* b_lds = smem + 32768;    // [128][128] bf16 swizzled (32KB)
  const int tid = threadIdx.x, lane = tid & 63, wid = tid >> 6;
  const int wm = wid >> 1, wn = wid & 1;
  const int r0 = blockIdx.x * 128, n0 = blockIdx.y * 128;
  const unsigned short* hs = (const unsigned short*)(ws + HS_OFF);
  const unsigned short* WyT = (const unsigned short*)(ws + WY_OFF);

  typedef float f32x16 __attribute__((ext_vector_type(16)));
  f32x16 acc[2][2] = {};
  for (int k0 = 0; k0 < 512; k0 += 128) {
#pragma unroll
    for (int i = 0; i < 8; ++i) {
      int base = i * 4096 + wid * 1024;
      int byte = base + lane * 16;
      int row = byte >> 8;
      int kb = (byte >> 4) & 15;
      gld_lds16(hs + (size_t)(r0 + row) * 512 + k0 + ((kb ^ (row & 15)) * 8), a_lds + base);
      gld_lds16(WyT + (size_t)(n0 + row) * 512 + k0 + ((kb ^ (row & 15)) * 8), b_lds + base);
    }
    __syncthreads();
#pragma unroll
    for (int kk = 0; kk < 8; ++kk) {
      int kbW = kk * 2 + (lane >> 5);
      short8 a[2], b[2];
#pragma unroll
      for (int mt = 0; mt < 2; ++mt) {
        int row = wm * 64 + mt * 32 + (lane & 31);
        a[mt] = *(const short8*)(a_lds + row * 256 + ((kbW ^ (row & 15)) * 16));
        int n = wn * 64 + mt * 32 + (lane & 31);
        b[mt] = *(const short8*)(b_lds + n * 256 + ((kbW ^ (n & 15)) * 16));
      }
#pragma unroll
      for (int mt = 0; mt < 2; ++mt)
#pragma unroll
        for (int nt = 0; nt < 2; ++nt)
          acc[mt][nt] = __builtin_amdgcn_mfma_f32_32x32x16_bf16(a[mt], b[nt], acc[mt][nt], 0, 0, 0);
    }
    __syncthreads();
  }
#pragma unroll
  for (int nt = 0; nt < 2; ++nt) {
    int o = n0 + wn * 64 + nt * 32 + (lane & 31);
    float bv = by[o];
#pragma unroll
    for (int mt = 0; mt < 2; ++mt)
#pragma unroll
      for (int rg = 0; rg < 16; ++rg) {
        int r = r0 + wm * 64 + mt * 32 + (rg & 3) + 8 * (rg >> 2) + 4 * (lane >> 5);
        out[(size_t)r * 256 + o] = acc[mt][nt][rg] + bv;
      }
  }
}

extern "C" void kernel_launch(void* const* d_in, const int* in_sizes, int n_in,
                              void* d_out, int out_size, void* d_ws, size_t ws_size,
                              hipStream_t stream) {
  (void)in_sizes; (void)n_in; (void)out_size; (void)ws_size;
  const float* x   = (const float*)d_in[0];
  const float* h0  = (const float*)d_in[1];
  const float* c0  = (const float*)d_in[2];
  const float* Wx  = (const float*)d_in[3];
  const float* Uh  = (const float*)d_in[4];
  const float* bih = (const float*)d_in[5];
  const float* bhh = (const float*)d_in[6];
  const float* Wy  = (const float*)d_in[7];
  const float* by  = (const float*)d_in[8];
  char* ws = (char*)d_ws;
  float* out = (float*)d_out;

  prep_kernel<<<1024, 256, 0, stream>>>(Wx, Uh, bih, bhh, Wy, h0, ws);
  xproj_kernel<<<dim3(256, 16), 256, 131072, stream>>>(x, ws);
  lstm_rec_kernel<<<256, 256, 32768, stream>>>(c0, ws, out);
  ygemm_kernel<<<dim3(256, 2), 256, 65536, stream>>>(ws, by, out);
}

// Round 16
// 1691.901 us; speedup vs baseline: 1.6797x; 1.5476x over previous
//
#include <hip/hip_runtime.h>

typedef short short8 __attribute__((ext_vector_type(8)));
typedef float f32x4 __attribute__((ext_vector_type(4)));

#define AS1 __attribute__((address_space(1)))
#define AS3 __attribute__((address_space(3)))

// ---- workspace layout (bytes) ----
static constexpr size_t XP_OFF = 0;            // xp bf16 [T=512][G=16][B=64][Q=128] 134217728
static constexpr size_t HS_OFF = 134217728;    // hs bf16 [B*T=32768][H=512]          33554432
static constexpr size_t U_OFF  = 167772160;    // U  bf16 [P=2048][K=512]              2097152
static constexpr size_t WX_OFF = 169869312;    // WxT bf16 [P=2048][K=256]             1048576
static constexpr size_t WY_OFF = 170917888;    // WyT bf16 [N=256][K=512]               262144
static constexpr size_t BI_OFF = 171180032;    // bias fp32 [2048] (permuted)             8192
static constexpr size_t HB_OFF = 171188224;    // h ping-pong bf16 2 x [64][512]         131072
static constexpr size_t FL_OFF = 171319296;    // step flags [4 rings][16] x 64B          4096
static constexpr size_t TB_OFF = 171323392;    // xcc table [256] u32                     1024
static constexpr size_t PR_OFF = 171324416;    // probe [64] x 64B                        4096
static constexpr size_t RS_OFF = 171328512;    // probe results [64] x 64B                4096

static __device__ __forceinline__ unsigned short f2bf(float f) {
  unsigned u = __float_as_uint(f);
  unsigned r = (u + 0x7fffu + ((u >> 16) & 1u)) >> 16;
  return (unsigned short)r;
}
static __device__ __forceinline__ float bf2f(unsigned short s) {
  return __uint_as_float(((unsigned)s) << 16);
}
static __device__ __forceinline__ float sigf(float x) { return 1.0f / (1.0f + __expf(-x)); }
static __device__ __forceinline__ float tanhf_(float x) { return 1.0f - 2.0f / (1.0f + __expf(2.0f * x)); }

static __device__ __forceinline__ void gld_lds16(const void* g, void* l) {
  __builtin_amdgcn_global_load_lds((const AS1 unsigned int*)g, (AS3 unsigned int*)l, 16, 0, 0);
}
// staging load: SLOW -> sc0|sc1 (device/MALL, R2/R6-proven), FAST -> sc0 (XCD-L2, R9-proven)
template<int SLOW>
static __device__ __forceinline__ void gld_lds16_c(const void* g, void* l) {
  if constexpr (SLOW)
    __builtin_amdgcn_global_load_lds((const AS1 unsigned int*)g, (AS3 unsigned int*)l, 16, 0, 17);
  else
    __builtin_amdgcn_global_load_lds((const AS1 unsigned int*)g, (AS3 unsigned int*)l, 16, 0, 1);
}
template<int SLOW>
static __device__ __forceinline__ unsigned ldflag(const unsigned* p) {
  unsigned r;
  if constexpr (SLOW)
    r = __hip_atomic_load(p, __ATOMIC_RELAXED, __HIP_MEMORY_SCOPE_AGENT);
  else
    asm volatile("global_load_dword %0, %1, off sc0\n\ts_waitcnt vmcnt(0)"
                 : "=v"(r) : "v"(p) : "memory");
  return r;
}
template<int SLOW>
static __device__ __forceinline__ void stflag(unsigned* p, unsigned v) {
  if constexpr (SLOW)
    __hip_atomic_store(p, v, __ATOMIC_RELAXED, __HIP_MEMORY_SCOPE_AGENT);
  else
    asm volatile("global_store_dword %0, %1, off sc0" :: "v"(p), "v"(v) : "memory");
}
template<int SLOW>
static __device__ __forceinline__ void sth32(void* p, unsigned v) {
  if constexpr (SLOW)
    __hip_atomic_store((unsigned*)p, v, __ATOMIC_RELAXED, __HIP_MEMORY_SCOPE_AGENT);
  else
    asm volatile("global_store_dword %0, %1, off sc0" :: "v"(p), "v"(v) : "memory");
}

#define DO16(M) M(0) M(1) M(2) M(3) M(4) M(5) M(6) M(7) M(8) M(9) M(10) M(11) \
  M(12) M(13) M(14) M(15)

// permuted gate column: packed p = g*128 + q, q = gate*32 + jl ; j = 32g + jl
static __device__ __forceinline__ unsigned orig_col(unsigned p) {
  return ((p & 127u) >> 5) * 512u + (p >> 7) * 32u + (p & 31u);
}

// ---------------- prep: pack weights to bf16 (permuted), biases, h0, control ----------------
__global__ void prep_kernel(const float* __restrict__ Wx, const float* __restrict__ Uh,
                            const float* __restrict__ bih, const float* __restrict__ bhh,
                            const float* __restrict__ Wy, const float* __restrict__ h0,
                            char* __restrict__ ws) {
  unsigned idx0 = blockIdx.x * blockDim.x + threadIdx.x;
  unsigned stride = gridDim.x * blockDim.x;
  unsigned short* Up = (unsigned short*)(ws + U_OFF);     // [p][k]
  for (unsigned i = idx0; i < 1048576u; i += stride) {
    unsigned k = i & 511u, p = i >> 9;
    Up[i] = f2bf(Uh[k * 2048u + orig_col(p)]);
  }
  unsigned short* Wxp = (unsigned short*)(ws + WX_OFF);   // [p][k]
  for (unsigned i = idx0; i < 524288u; i += stride) {
    unsigned k = i & 255u, p = i >> 8;
    Wxp[i] = f2bf(Wx[k * 2048u + orig_col(p)]);
  }
  unsigned short* Wyp = (unsigned short*)(ws + WY_OFF);   // [n][k]
  for (unsigned i = idx0; i < 131072u; i += stride) {
    unsigned k = i & 511u, n = i >> 9;
    Wyp[i] = f2bf(Wy[k * 256u + n]);
  }
  float* bp = (float*)(ws + BI_OFF);
  for (unsigned p = idx0; p < 2048u; p += stride) {
    unsigned c = orig_col(p);
    bp[p] = bih[c] + bhh[c];
  }
  unsigned short* hb = (unsigned short*)(ws + HB_OFF);
  for (unsigned i = idx0; i < 32768u; i += stride) hb[i] = f2bf(h0[i]);
  // zero flags + tbl + probe + res (13312 B = 3328 u32)
  for (unsigned i = idx0; i < 3328u; i += stride)
    ((unsigned*)(ws + FL_OFF))[i] = 0u;
}

// ---------------- xproj: xp[t][g=p>>7][b][q=p&127] (bf16) = x @ WxT + bias ----------------
__launch_bounds__(256, 1)
__global__ void xproj_kernel(const float* __restrict__ x, char* __restrict__ ws) {
  extern __shared__ char smem[];
  char* a_lds = smem;            // [128 r][256 k] bf16 swizzled (64KB)
  char* b_lds = smem + 65536;    // [128 p][256 k] bf16 swizzled (64KB)
  const int tid = threadIdx.x, lane = tid & 63, wid = tid >> 6;
  const int wm = wid >> 1, wn = wid & 1;
  const int r0 = blockIdx.x * 128, p0 = blockIdx.y * 128;
  const unsigned short* WxT = (const unsigned short*)(ws + WX_OFF);

#pragma unroll
  for (int i = 0; i < 16; ++i) {
    int base = i * 4096 + wid * 1024;
    int byte = base + lane * 16;
    int row = byte >> 9;
    int kb = (byte >> 4) & 31;
    gld_lds16(WxT + (size_t)(p0 + row) * 256 + (size_t)((kb ^ (row & 15)) * 8), b_lds + base);
  }
  {
    int row = tid >> 1, half = tid & 1;
    const float* xr = x + (size_t)(r0 + row) * 256 + half * 128;
    char* ar = a_lds + row * 512;
#pragma unroll
    for (int i = 0; i < 16; ++i) {
      float4 f0 = *(const float4*)(xr + i * 8);
      float4 f1 = *(const float4*)(xr + i * 8 + 4);
      short8 v;
      v[0] = (short)f2bf(f0.x); v[1] = (short)f2bf(f0.y); v[2] = (short)f2bf(f0.z); v[3] = (short)f2bf(f0.w);
      v[4] = (short)f2bf(f1.x); v[5] = (short)f2bf(f1.y); v[6] = (short)f2bf(f1.z); v[7] = (short)f2bf(f1.w);
      int kb = half * 16 + i;
      *(short8*)(ar + ((kb ^ (row & 15)) * 16)) = v;
    }
  }
  __syncthreads();

  typedef float f32x16 __attribute__((ext_vector_type(16)));
  f32x16 acc[2][2] = {};
#pragma unroll
  for (int kk = 0; kk < 16; ++kk) {
    int kbW = kk * 2 + (lane >> 5);
    short8 a[2], b[2];
#pragma unroll
    for (int mt = 0; mt < 2; ++mt) {
      int row = wm * 64 + mt * 32 + (lane & 31);
      a[mt] = *(const short8*)(a_lds + row * 512 + ((kbW ^ (row & 15)) * 16));
    }
#pragma unroll
    for (int nt = 0; nt < 2; ++nt) {
      int n = wn * 64 + nt * 32 + (lane & 31);
      b[nt] = *(const short8*)(b_lds + n * 512 + ((kbW ^ (n & 15)) * 16));
    }
#pragma unroll
    for (int mt = 0; mt < 2; ++mt)
#pragma unroll
      for (int nt = 0; nt < 2; ++nt)
        acc[mt][nt] = __builtin_amdgcn_mfma_f32_32x32x16_bf16(a[mt], b[nt], acc[mt][nt], 0, 0, 0);
  }

  const float* bias = (const float*)(ws + BI_OFF);
  unsigned short* xp = (unsigned short*)(ws + XP_OFF);
#pragma unroll
  for (int nt = 0; nt < 2; ++nt) {
    int p = p0 + wn * 64 + nt * 32 + (lane & 31);
    float bv = bias[p];
    int g = p >> 7, q = p & 127;
#pragma unroll
    for (int mt = 0; mt < 2; ++mt) {
#pragma unroll
      for (int rg = 0; rg < 16; ++rg) {
        int r = r0 + wm * 64 + mt * 32 + (rg & 3) + 8 * (rg >> 2) + 4 * (lane >> 5);
        int b = r >> 9, t = r & 511;
        xp[((size_t)(t * 16 + g) * 64 + b) * 128 + q] = f2bf(acc[mt][nt][rg] + bv);
      }
    }
  }
}

// ---------------- recurrence main loop (R6-proven protocol; ring-local, scope templated) ----------------
// wg (ring, g): batch rows [16*ring, +16), packed gate cols [128g, +128) (= j in [32g,+32)).
// Rings (batch groups) are fully independent: consumers poll only their ring's 16 producers.
template<int SLOW>
static __device__ __forceinline__ void run_loop(char* smem, const float* c0, char* ws,
                                                float* out, int tid, int ring, int g) {
  char* h_lds = smem;                        // [16][512] bf16 swizzled (16KB)
  float* gates = (float*)(smem + 16384);     // [16][132] fp32 (8448B)
  const int lane = tid & 63, wid = tid >> 6;
  const int bq16 = ring * 16;
  char* hbuf = ws + HB_OFF;
  const unsigned short* xp = (const unsigned short*)(ws + XP_OFF);
  unsigned short* hs = (unsigned short*)(ws + HS_OFF);
  unsigned* flags = (unsigned*)(ws + FL_OFF);
  unsigned* myflag = flags + (size_t)(ring * 16 + g) * 16;
  unsigned* pollp = flags + (size_t)(ring * 16 + (lane & 15)) * 16;

  // B panels: wave wid owns packed cols [g*128 + wid*32, +32); 32 frags pinned in 128 VGPRs.
  short8 bU[32];   // fi = nt*16 + ks
  {
    const unsigned short* Up = (const unsigned short*)(ws + U_OFF);
    const unsigned short* pu0 = Up + (size_t)(g * 128 + wid * 32 + (lane & 15)) * 512 + (lane >> 4) * 8;
    const unsigned short* pu1 = pu0 + 16 * 512;
#define LDU0(k) asm volatile("global_load_dwordx4 %0, %1, off offset:%c2" \
                             : "=v"(bU[k]) : "v"(pu0), "i"((k) * 64) : "memory");
#define LDU1(k) asm volatile("global_load_dwordx4 %0, %1, off offset:%c2" \
                             : "=v"(bU[16 + (k)]) : "v"(pu1), "i"((k) * 64) : "memory");
    DO16(LDU0)
    DO16(LDU1)
#undef LDU0
#undef LDU1
    asm volatile("s_waitcnt vmcnt(0)" ::: "memory");
    __builtin_amdgcn_sched_barrier(0);
  }
  // elementwise ownership: thread -> (b = bq16 + bl, j = 32g + jlp, jlp+1); c in regs
  const int bl = tid >> 4, jlp = (tid & 15) * 2;
  float2 cp = *(const float2*)(c0 + (size_t)(bq16 + bl) * 512 + g * 32 + jlp);
  float cc0 = cp.x, cc1 = cp.y;

  for (int t = 0; t < 512; ++t) {
    // xp for this thread's 2 cells x 4 gates (plain cached; overlaps poll)
    const unsigned short* xpt = xp + ((size_t)(t * 16 + g) * 64 + (bq16 + bl)) * 128;
    ushort2 xi2 = *(const ushort2*)(xpt + jlp);
    ushort2 xf2 = *(const ushort2*)(xpt + 32 + jlp);
    ushort2 xj2 = *(const ushort2*)(xpt + 64 + jlp);
    ushort2 xo2 = *(const ushort2*)(xpt + 96 + jlp);

    // wait: all 16 ring producers' flags >= t (wave 0 only)
    if (wid == 0) {
      unsigned tgt = (unsigned)t;
      while (__any(ldflag<SLOW>(pollp) < tgt)) {}
    }
    __syncthreads();

    // stage ring's 16 rows of slot t&1 into LDS (pre-swizzled source; wave wid rows [4wid,+4))
    const char* hb = hbuf + (t & 1) * 65536;
#pragma unroll
    for (int i = 0; i < 4; ++i) {
      int r = wid * 4 + i;
      gld_lds16_c<SLOW>(hb + (size_t)(bq16 + r) * 1024 + ((lane ^ r) * 16), h_lds + r * 1024);
    }
    __syncthreads();  // compiler drains vmcnt before s_barrier

    // GEMM [16 x 512] x [512 x 128]: per wave 2 N-tiles x 16 k-steps of 16x16x32
    f32x4 ac[2][2] = {};
#pragma unroll
    for (int ks = 0; ks < 16; ++ks) {
      int row = lane & 15;
      int gi = (ks * 4 + (lane >> 4)) ^ row;
      short8 a = *(const short8*)(h_lds + row * 1024 + gi * 16);
      ac[0][ks & 1] = __builtin_amdgcn_mfma_f32_16x16x32_bf16(a, bU[ks], ac[0][ks & 1], 0, 0, 0);
      ac[1][ks & 1] = __builtin_amdgcn_mfma_f32_16x16x32_bf16(a, bU[16 + ks], ac[1][ks & 1], 0, 0, 0);
    }
#pragma unroll
    for (int nt = 0; nt < 2; ++nt) {
      f32x4 acc = ac[nt][0] + ac[nt][1];
      int pl = wid * 32 + nt * 16 + (lane & 15);
      int rb = (lane >> 4) * 4;
#pragma unroll
      for (int rg = 0; rg < 4; ++rg)
        gates[(rb + rg) * 132 + pl] = acc[rg];
    }
    __syncthreads();

    // elementwise LSTM cell: 2 cells/thread
    const float* gr = gates + bl * 132;
    float2 gi2 = *(const float2*)(gr + jlp);
    float2 gf2 = *(const float2*)(gr + 32 + jlp);
    float2 gj2 = *(const float2*)(gr + 64 + jlp);
    float2 go2 = *(const float2*)(gr + 96 + jlp);
    float i0 = sigf(gi2.x + bf2f(xi2.x)), i1 = sigf(gi2.y + bf2f(xi2.y));
    float f0 = sigf(gf2.x + bf2f(xf2.x)), f1 = sigf(gf2.y + bf2f(xf2.y));
    float j0v = tanhf_(gj2.x + bf2f(xj2.x)), j1v = tanhf_(gj2.y + bf2f(xj2.y));
    float o0 = sigf(go2.x + bf2f(xo2.x)), o1 = sigf(go2.y + bf2f(xo2.y));
    cc0 = f0 * cc0 + i0 * j0v;
    cc1 = f1 * cc1 + i1 * j1v;
    float h0v = o0 * tanhf_(cc0);
    float h1v = o1 * tanhf_(cc1);
    unsigned hv = (unsigned)f2bf(h0v) | ((unsigned)f2bf(h1v) << 16);

    // h -> ping-pong slot (t+1)&1 (scope-matched store), hs record, final outputs
    if (t < 511)
      sth32<SLOW>(hbuf + ((t + 1) & 1) * 65536 +
                  ((size_t)(bq16 + bl) * 512 + g * 32 + jlp) * 2, hv);
    *(unsigned*)(hs + ((size_t)(bq16 + bl) * 512 + t) * 512 + g * 32 + jlp) = hv;
    if (t == 511) {
      *(float2*)(out + 8388608u + (size_t)(bq16 + bl) * 512 + g * 32 + jlp) = make_float2(h0v, h1v);
      *(float2*)(out + 8421376u + (size_t)(bq16 + bl) * 512 + g * 32 + jlp) = make_float2(cc0, cc1);
    }
    // drain own stores to the mode's coherent point, then publish (store, no RMW)
    asm volatile("s_waitcnt vmcnt(0)" ::: "memory");
    __syncthreads();
    if (tid == 0) stflag<SLOW>(myflag, (unsigned)(t + 1));
  }
}

// 256 wgs register their XCD; all derive the same assignment: 4 rings x 16 members,
// each ring on one XCD (first 4 XCD values with >=16 wgs; else forced-slow on bids 0..63).
// Each ring independently probes sc0 visibility (bounded) and collectively picks
// fast (XCD-L2) or slow (device-scope, R6-proven). Rings never communicate.
__launch_bounds__(256, 1)
__global__ void lstm_rec_kernel(const float* __restrict__ c0, char* __restrict__ ws,
                                float* __restrict__ out) {
  extern __shared__ char smem[];   // h 16KB | gates 8448 | ldsT 1024 | ldsF 64
  unsigned* ldsT = (unsigned*)(smem + 16384 + 8448);
  unsigned* ldsF = (unsigned*)(smem + 16384 + 8448 + 1024);
  const int tid = threadIdx.x, lane = tid & 63, wid = tid >> 6;
  const int bid = blockIdx.x;

  // phase 0: registration (R9-proven)
  unsigned* tbl = (unsigned*)(ws + TB_OFF);
  unsigned xcc;
  asm volatile("s_getreg_b32 %0, hwreg(HW_REG_XCC_ID)" : "=s"(xcc));
  if (tid == 0)
    __hip_atomic_store(tbl + bid, (xcc & 15u) + 1u, __ATOMIC_RELAXED, __HIP_MEMORY_SCOPE_AGENT);
  if (wid == 0) {
    for (;;) {
      unsigned v0 = __hip_atomic_load(tbl + lane, __ATOMIC_RELAXED, __HIP_MEMORY_SCOPE_AGENT);
      unsigned v1 = __hip_atomic_load(tbl + 64 + lane, __ATOMIC_RELAXED, __HIP_MEMORY_SCOPE_AGENT);
      unsigned v2 = __hip_atomic_load(tbl + 128 + lane, __ATOMIC_RELAXED, __HIP_MEMORY_SCOPE_AGENT);
      unsigned v3 = __hip_atomic_load(tbl + 192 + lane, __ATOMIC_RELAXED, __HIP_MEMORY_SCOPE_AGENT);
      ldsT[lane] = v0; ldsT[64 + lane] = v1; ldsT[128 + lane] = v2; ldsT[192 + lane] = v3;
      if (__all((v0 != 0u) && (v1 != 0u) && (v2 != 0u) && (v3 != 0u))) break;
    }
  }
  __syncthreads();

  // phase 1: deterministic assignment (identical on every thread)
  int ringXcd[4] = {0, 0, 0, 0};
  int nr = 0;
  for (int x = 1; x <= 16; ++x) {
    int cnt = 0;
    for (int b = 0; b < 256; ++b) cnt += (ldsT[b] == (unsigned)x) ? 1 : 0;
    if (cnt >= 16 && nr < 4) ringXcd[nr++] = x;
  }
  bool slowForce = (nr < 4);
  int ring = 0, g = 0;
  bool sel = false;
  if (slowForce) {
    sel = (bid < 64);
    ring = bid >> 4;
    g = bid & 15;
  } else {
    unsigned myx = ldsT[bid];
    int r = -1;
    for (int i = 0; i < 4; ++i)
      if (ringXcd[i] == (int)myx) r = i;
    if (r >= 0) {
      int rank = 0;
      for (int b = 0; b < bid; ++b) rank += (ldsT[b] == myx) ? 1 : 0;
      if (rank < 16) { sel = true; ring = r; g = rank; }
    }
  }
  if (!sel) return;

  // phase 2: per-ring bounded probe of sc0 visibility, then collective decision (device-scope)
  bool fast = false;
  if (!slowForce) {
    unsigned* probe = (unsigned*)(ws + PR_OFF);
    if (tid == 0) stflag<0>(probe + (size_t)(ring * 16 + g) * 16, 1u);
    asm volatile("s_waitcnt vmcnt(0)" ::: "memory");
    if (wid == 0) {
      int ok = 0;
      for (int it = 0; it < 4096; ++it) {
        unsigned v = ldflag<0>(probe + (size_t)(ring * 16 + (lane & 15)) * 16);
        if (__all(v != 0u)) { ok = 1; break; }
      }
      if (lane == 0) ldsF[0] = (unsigned)ok;
    }
    __syncthreads();
    unsigned ok = ldsF[0];
    unsigned* res = (unsigned*)(ws + RS_OFF);
    if (tid == 0) stflag<1>(res + (size_t)(ring * 16 + g) * 16, ok ? 2u : 1u);
    if (wid == 0) {
      unsigned v;
      do {
        v = ldflag<1>(res + (size_t)(ring * 16 + (lane & 15)) * 16);
      } while (__any(v == 0u));
      if (lane == 0) ldsF[1] = __all(v == 2u) ? 1u : 0u;
    }
    __syncthreads();
    fast = (ldsF[1] != 0u);
  }

  if (fast) run_loop<0>(smem, c0, (char*)ws, out, tid, ring, g);
  else      run_loop<1>(smem, c0, (char*)ws, out, tid, ring, g);
}

// ---------------- ygemm: out[r][o] = hs @ WyT + b_y ----------------
__launch_bounds__(256, 1)
__global__ void ygemm_kernel(const char* __restrict__ ws, const float* __restrict__ by,
                             float* __restrict__ out) {
  extern __shared__ char smem[];
  char* a_lds = smem;            // [128][128] bf16 swizzled (32KB)
  char* b_lds = smem + 32768;    // [128][128] bf16 swizzled (32KB)
  const int tid = threadIdx.x, lane = tid & 63, wid = tid >> 6;
  const int wm = wid >> 1, wn = wid & 1;
  const int r0 = blockIdx.x * 128, n0 = blockIdx.y * 128;
  const unsigned short* hs = (const unsigned short*)(ws + HS_OFF);
  const unsigned short* WyT = (const unsigned short*)(ws + WY_OFF);

  typedef float f32x16 __attribute__((ext_vector_type(16)));
  f32x16 acc[2][2] = {};
  for (int k0 = 0; k0 < 512; k0 += 128) {
#pragma unroll
    for (int i = 0; i < 8; ++i) {
      int base = i * 4096 + wid * 1024;
      int byte = base + lane * 16;
      int row = byte >> 8;
      int kb = (byte >> 4) & 15;
      gld_lds16(hs + (size_t)(r0 + row) * 512 + k0 + ((kb ^ (row & 15)) * 8), a_lds + base);
      gld_lds16(WyT + (size_t)(n0 + row) * 512 + k0 + ((kb ^ (row & 15)) * 8), b_lds + base);
    }
    __syncthreads();
#pragma unroll
    for (int kk = 0; kk < 8; ++kk) {
      int kbW = kk * 2 + (lane >> 5);
      short8 a[2], b[2];
#pragma unroll
      for (int mt = 0; mt < 2; ++mt) {
        int row = wm * 64 + mt * 32 + (lane & 31);
        a[mt] = *(const short8*)(a_lds + row * 256 + ((kbW ^ (row & 15)) * 16));
        int n = wn * 64 + mt * 32 + (lane & 31);
        b[mt] = *(const short8*)(b_lds + n * 256 + ((kbW ^ (n & 15)) * 16));
      }
#pragma unroll
      for (int mt = 0; mt < 2; ++mt)
#pragma unroll
        for (int nt = 0; nt < 2; ++nt)
          acc[mt][nt] = __builtin_amdgcn_mfma_f32_32x32x16_bf16(a[mt], b[nt], acc[mt][nt], 0, 0, 0);
    }
    __syncthreads();
  }
#pragma unroll
  for (int nt = 0; nt < 2; ++nt) {
    int o = n0 + wn * 64 + nt * 32 + (lane & 31);
    float bv = by[o];
#pragma unroll
    for (int mt = 0; mt < 2; ++mt)
#pragma unroll
      for (int rg = 0; rg < 16; ++rg) {
        int r = r0 + wm * 64 + mt * 32 + (rg & 3) + 8 * (rg >> 2) + 4 * (lane >> 5);
        out[(size_t)r * 256 + o] = acc[mt][nt][rg] + bv;
      }
  }
}

extern "C" void kernel_launch(void* const* d_in, const int* in_sizes, int n_in,
                              void* d_out, int out_size, void* d_ws, size_t ws_size,
                              hipStream_t stream) {
  (void)in_sizes; (void)n_in; (void)out_size; (void)ws_size;
  const float* x   = (const float*)d_in[0];
  const float* h0  = (const float*)d_in[1];
  const float* c0  = (const float*)d_in[2];
  const float* Wx  = (const float*)d_in[3];
  const float* Uh  = (const float*)d_in[4];
  const float* bih = (const float*)d_in[5];
  const float* bhh = (const float*)d_in[6];
  const float* Wy  = (const float*)d_in[7];
  const float* by  = (const float*)d_in[8];
  char* ws = (char*)d_ws;
  float* out = (float*)d_out;

  prep_kernel<<<1024, 256, 0, stream>>>(Wx, Uh, bih, bhh, Wy, h0, ws);
  xproj_kernel<<<dim3(256, 16), 256, 131072, stream>>>(x, ws);
  lstm_rec_kernel<<<256, 256, 16384 + 8448 + 1024 + 64, stream>>>(c0, ws, out);
  ygemm_kernel<<<dim3(256, 2), 256, 65536, stream>>>(ws, by, out);
}